// Round 1
// baseline (362.128 us; speedup 1.0000x reference)
//
#include <hip/hip_runtime.h>

// Problem constants (from reference): N=262144, D=256, L=2, E=64
// d_in: [0]=x (N*D f32), [1]=individual_idx (N i32), [2]=enc_W (E*L*D f32),
//       [3]=enc_b (E*L f32), [4]=dec_W (L f32), [5]=dec_b (1 f32)
// d_out: y (N f32) followed by z (N*L f32), concatenated flat.

#define D_DIM 256
#define L_DIM 2

__global__ __launch_bounds__(256) void multi_encoder_yaw_kernel(
    const float* __restrict__ x,
    const int* __restrict__ idx,
    const float* __restrict__ encW,   // [E, L, D] = [E, 2, 256]
    const float* __restrict__ encb,   // [E, 2]
    const float* __restrict__ decW,   // [2]
    const float* __restrict__ decb,   // [1]
    float* __restrict__ y,            // [N]
    float* __restrict__ z,            // [N, 2]
    int n_rows)
{
    const int gtid = blockIdx.x * blockDim.x + threadIdx.x;
    const int row  = gtid >> 6;       // one wave (64 lanes) per row
    const int lane = threadIdx.x & 63;
    if (row >= n_rows) return;

    const int e = idx[row];           // wave-uniform in practice (same row)

    // Lane i covers elements [4i, 4i+4) of the 256-wide row.
    const float4 xv = *(const float4*)(x + (size_t)row * D_DIM + lane * 4);
    const float* we = encW + (size_t)e * (L_DIM * D_DIM);
    const float4 w0 = *(const float4*)(we + lane * 4);            // l=0 row
    const float4 w1 = *(const float4*)(we + D_DIM + lane * 4);    // l=1 row

    float z0 = xv.x * w0.x + xv.y * w0.y + xv.z * w0.z + xv.w * w0.w;
    float z1 = xv.x * w1.x + xv.y * w1.y + xv.z * w1.z + xv.w * w1.w;

    // Butterfly reduction across the 64-lane wave (both accumulators).
    #pragma unroll
    for (int off = 32; off > 0; off >>= 1) {
        z0 += __shfl_down(z0, off, 64);
        z1 += __shfl_down(z1, off, 64);
    }

    if (lane == 0) {
        z0 += encb[e * L_DIM + 0];
        z1 += encb[e * L_DIM + 1];
        z[(size_t)row * L_DIM + 0] = z0;
        z[(size_t)row * L_DIM + 1] = z1;
        y[row] = z0 * decW[0] + z1 * decW[1] + decb[0];
    }
}

extern "C" void kernel_launch(void* const* d_in, const int* in_sizes, int n_in,
                              void* d_out, int out_size, void* d_ws, size_t ws_size,
                              hipStream_t stream) {
    const float* x    = (const float*)d_in[0];
    const int*   idx  = (const int*)d_in[1];
    const float* encW = (const float*)d_in[2];
    const float* encb = (const float*)d_in[3];
    const float* decW = (const float*)d_in[4];
    const float* decb = (const float*)d_in[5];

    const int n_rows = in_sizes[1];           // N from individual_idx
    float* y = (float*)d_out;                 // [N]
    float* z = (float*)d_out + n_rows;        // [N, 2]

    // One wave per row; 4 waves per 256-thread block.
    const int rows_per_block = 256 / 64;
    const int grid = (n_rows + rows_per_block - 1) / rows_per_block;
    multi_encoder_yaw_kernel<<<grid, 256, 0, stream>>>(
        x, idx, encW, encb, decW, decb, y, z, n_rows);
}